// Round 1
// baseline (341.757 us; speedup 1.0000x reference)
//
#include <hip/hip_runtime.h>
#include <hip/hip_bf16.h>
#include <cstdio>

// ---------------------------------------------------------------------------
// HAttention1D: B=4 N=4096 DIM=1024 HEADS=8 DH=64 BSZ=16, 8 levels (0..7)
// Pipeline:
//  1) f2b: x, w_qkv, w_out -> bf16
//  2) gemm_qkv (bf16 MFMA): qkv = x @ w_qkv^T, epilogue scatters q*0.125,k,v
//     into (bh, row, d) pyramids (level-0 region)
//  3) pyramid x7: level l from l-1 (q,k mean; v sum), bf16
//  4) attn: per (level-block, bh): S=q@k^T (sibling-flipped keys for l>=1),
//     A=exp(S), y=A@v, a=rowsum(A)   (fp32 math, bf16 operands)
//  5) combine: U = sum_l y_l[i>>l] / (sum_l a_l[i>>l] + eps) -> bf16 [m, h*64+d]
//  6) gemm_out (bf16 MFMA): out = U @ w_out^T + b_out (fp32 out)
// ---------------------------------------------------------------------------

typedef __bf16 bf16x8 __attribute__((ext_vector_type(8)));
typedef float floatx4 __attribute__((ext_vector_type(4)));

#define ROWS_PER_BH 8160  // 4096+2048+1024+512+256+128+64+32

__device__ __forceinline__ void g2lds16(const void* g, void* l) {
  __builtin_amdgcn_global_load_lds(
      (const __attribute__((address_space(1))) void*)g,
      (__attribute__((address_space(3))) void*)l, 16, 0, 0);
}

// ---- fp32 -> bf16 convert, 4 elems/thread ---------------------------------
__global__ __launch_bounds__(256) void f2b_kernel(const float* __restrict__ s,
                                                  __hip_bfloat16* __restrict__ d,
                                                  int n) {
  int i0 = (blockIdx.x * 256 + threadIdx.x) * 4;
  if (i0 + 3 < n) {
    float4 v = *(const float4*)(s + i0);
    d[i0 + 0] = __float2bfloat16(v.x);
    d[i0 + 1] = __float2bfloat16(v.y);
    d[i0 + 2] = __float2bfloat16(v.z);
    d[i0 + 3] = __float2bfloat16(v.w);
  }
}

// ---- GEMM1: qkv = x[16384,1024] @ w_qkv[1536,1024]^T, scatter epilogue ----
__global__ __launch_bounds__(256) void gemm_qkv_kernel(
    const unsigned short* __restrict__ A,   // xb [16384,1024] bf16
    const unsigned short* __restrict__ B,   // wqkvb [1536,1024] bf16
    __hip_bfloat16* __restrict__ qp, __hip_bfloat16* __restrict__ kp,
    __hip_bfloat16* __restrict__ vp) {
  const int K = 1024;
  __shared__ unsigned short ldsA[128 * 32];
  __shared__ unsigned short ldsB[128 * 32];
  const int tid = threadIdx.x;
  const int lane = tid & 63, w = tid >> 6;
  const int wm = w >> 1, wn = w & 1;
  const int tM = blockIdx.x * 128, tN = blockIdx.y * 128;

  const unsigned short* Ag = A + (size_t)(tM + w * 32 + (lane >> 2)) * K + (lane & 3) * 8;
  const unsigned short* Bg = B + (size_t)(tN + w * 32 + (lane >> 2)) * K + (lane & 3) * 8;
  unsigned short* lA = &ldsA[w * 1024 + lane * 8];
  unsigned short* lB = &ldsB[w * 1024 + lane * 8];

  floatx4 acc[4][4];
#pragma unroll
  for (int i = 0; i < 4; i++)
#pragma unroll
    for (int j = 0; j < 4; j++) acc[i][j] = (floatx4){0.f, 0.f, 0.f, 0.f};

  const int rA = wm * 64 + (lane & 15);
  const int rB = wn * 64 + (lane & 15);
  const int kc = (lane >> 4) * 8;

  for (int kt = 0; kt < K; kt += 32) {
    __syncthreads();
    g2lds16(Ag + kt, lA);
    g2lds16(Ag + 16 * K + kt, lA + 512);
    g2lds16(Bg + kt, lB);
    g2lds16(Bg + 16 * K + kt, lB + 512);
    __syncthreads();
    bf16x8 af[4], bv[4];
#pragma unroll
    for (int i = 0; i < 4; i++) af[i] = *(const bf16x8*)&ldsA[(rA + i * 16) * 32 + kc];
#pragma unroll
    for (int j = 0; j < 4; j++) bv[j] = *(const bf16x8*)&ldsB[(rB + j * 16) * 32 + kc];
#pragma unroll
    for (int i = 0; i < 4; i++)
#pragma unroll
      for (int j = 0; j < 4; j++)
        acc[i][j] = __builtin_amdgcn_mfma_f32_16x16x32_bf16(af[i], bv[j], acc[i][j], 0, 0, 0);
  }

  // epilogue: C/D layout col=lane&15, row=(lane>>4)*4+r  [verified m89]
  const int quad = lane >> 4;
#pragma unroll
  for (int i = 0; i < 4; i++) {
#pragma unroll
    for (int j = 0; j < 4; j++) {
      const int c = tN + wn * 64 + j * 16 + (lane & 15);
      const int tensor = c >> 9;         // 0=q 1=k 2=v
      const int rem = c & 511;
      const int h = rem >> 6, d = rem & 63;
      __hip_bfloat16* dstbuf = (tensor == 0) ? qp : ((tensor == 1) ? kp : vp);
      const float scale = (tensor == 0) ? 0.125f : 1.0f;  // DH^-0.5
#pragma unroll
      for (int r = 0; r < 4; r++) {
        const int m = tM + wm * 64 + i * 16 + quad * 4 + r;
        const int b = m >> 12, n = m & 4095;
        size_t dst = ((size_t)(b * 8 + h) * ROWS_PER_BH + n) * 64 + d;
        dstbuf[dst] = __float2bfloat16(acc[i][j][r] * scale);
      }
    }
  }
}

// ---- GEMM2: out = U[16384,512] @ w_out[1024,512]^T + b_out ----------------
__global__ __launch_bounds__(256) void gemm_out_kernel(
    const unsigned short* __restrict__ A,   // Ub [16384,512] bf16
    const unsigned short* __restrict__ B,   // wob [1024,512] bf16
    const float* __restrict__ bias, float* __restrict__ out) {
  const int K = 512;
  __shared__ unsigned short ldsA[128 * 32];
  __shared__ unsigned short ldsB[128 * 32];
  const int tid = threadIdx.x;
  const int lane = tid & 63, w = tid >> 6;
  const int wm = w >> 1, wn = w & 1;
  const int tM = blockIdx.x * 128, tN = blockIdx.y * 128;

  const unsigned short* Ag = A + (size_t)(tM + w * 32 + (lane >> 2)) * K + (lane & 3) * 8;
  const unsigned short* Bg = B + (size_t)(tN + w * 32 + (lane >> 2)) * K + (lane & 3) * 8;
  unsigned short* lA = &ldsA[w * 1024 + lane * 8];
  unsigned short* lB = &ldsB[w * 1024 + lane * 8];

  floatx4 acc[4][4];
#pragma unroll
  for (int i = 0; i < 4; i++)
#pragma unroll
    for (int j = 0; j < 4; j++) acc[i][j] = (floatx4){0.f, 0.f, 0.f, 0.f};

  const int rA = wm * 64 + (lane & 15);
  const int rB = wn * 64 + (lane & 15);
  const int kc = (lane >> 4) * 8;

  for (int kt = 0; kt < K; kt += 32) {
    __syncthreads();
    g2lds16(Ag + kt, lA);
    g2lds16(Ag + 16 * K + kt, lA + 512);
    g2lds16(Bg + kt, lB);
    g2lds16(Bg + 16 * K + kt, lB + 512);
    __syncthreads();
    bf16x8 af[4], bv[4];
#pragma unroll
    for (int i = 0; i < 4; i++) af[i] = *(const bf16x8*)&ldsA[(rA + i * 16) * 32 + kc];
#pragma unroll
    for (int j = 0; j < 4; j++) bv[j] = *(const bf16x8*)&ldsB[(rB + j * 16) * 32 + kc];
#pragma unroll
    for (int i = 0; i < 4; i++)
#pragma unroll
      for (int j = 0; j < 4; j++)
        acc[i][j] = __builtin_amdgcn_mfma_f32_16x16x32_bf16(af[i], bv[j], acc[i][j], 0, 0, 0);
  }

  const int quad = lane >> 4;
#pragma unroll
  for (int i = 0; i < 4; i++) {
#pragma unroll
    for (int j = 0; j < 4; j++) {
      const int c = tN + wn * 64 + j * 16 + (lane & 15);
      const float bb = bias[c];
#pragma unroll
      for (int r = 0; r < 4; r++) {
        const int m = tM + wm * 64 + i * 16 + quad * 4 + r;
        out[(size_t)m * 1024 + c] = acc[i][j][r] + bb;
      }
    }
  }
}

// ---- pyramid: level l from level l-1 (q,k mean; v sum) --------------------
__global__ __launch_bounds__(256) void pyramid_kernel(
    __hip_bfloat16* __restrict__ qp, __hip_bfloat16* __restrict__ kp,
    __hip_bfloat16* __restrict__ vp, int srcRow, int dstRow, int nOut, int shift) {
  int idx = blockIdx.x * 256 + threadIdx.x;
  if (idx >= 32 * nOut * 64) return;
  int d = idx & 63;
  int i = (idx >> 6) & (nOut - 1);
  int bh = idx >> (6 + shift);
  size_t s0 = ((size_t)bh * ROWS_PER_BH + srcRow + 2 * i) * 64 + d;
  size_t dst = ((size_t)bh * ROWS_PER_BH + dstRow + i) * 64 + d;
  float q0 = __bfloat162float(qp[s0]), q1 = __bfloat162float(qp[s0 + 64]);
  float k0 = __bfloat162float(kp[s0]), k1 = __bfloat162float(kp[s0 + 64]);
  float v0 = __bfloat162float(vp[s0]), v1 = __bfloat162float(vp[s0 + 64]);
  qp[dst] = __float2bfloat16(0.5f * (q0 + q1));
  kp[dst] = __float2bfloat16(0.5f * (k0 + k1));
  vp[dst] = __float2bfloat16(v0 + v1);
}

// ---- block attention: one workgroup per (level-block, bh) -----------------
__global__ __launch_bounds__(256) void attn_kernel(
    const __hip_bfloat16* __restrict__ qp, const __hip_bfloat16* __restrict__ kp,
    const __hip_bfloat16* __restrict__ vp, float* __restrict__ yall,
    float* __restrict__ aall) {
  // stride 65 pad: kills the 16-way bank conflict on the k^T dot
  __shared__ float qs[16 * 65], ks[16 * 65], vs[16 * 65], As[16 * 17];
  const int bx = blockIdx.x, bh = blockIdx.y, tid = threadIdx.x;
  int level, blk;
  if (bx < 256)      { level = 0; blk = bx; }
  else if (bx < 384) { level = 1; blk = bx - 256; }
  else if (bx < 448) { level = 2; blk = bx - 384; }
  else if (bx < 480) { level = 3; blk = bx - 448; }
  else if (bx < 496) { level = 4; blk = bx - 480; }
  else if (bx < 504) { level = 5; blk = bx - 496; }
  else if (bx < 508) { level = 6; blk = bx - 504; }
  else               { level = 7; blk = bx - 508; }
  const int ro = 8192 - (8192 >> level);
  const int kblk = (level == 0) ? blk : (blk ^ 1);  // sibling key-block flip (v NOT flipped)
  const size_t qbase = ((size_t)bh * ROWS_PER_BH + ro + blk * 16) * 64;
  const size_t kbase = ((size_t)bh * ROWS_PER_BH + ro + kblk * 16) * 64;

  for (int e = tid; e < 1024; e += 256) {
    int r = e >> 6, d = e & 63;
    qs[r * 65 + d] = __bfloat162float(qp[qbase + e]);
    ks[r * 65 + d] = __bfloat162float(kp[kbase + e]);
    vs[r * 65 + d] = __bfloat162float(vp[qbase + e]);
  }
  __syncthreads();

  const int si = tid >> 4, sj = tid & 15;
  float s = 0.f;
#pragma unroll
  for (int d = 0; d < 64; d++) s += qs[si * 65 + d] * ks[sj * 65 + d];
  As[si * 17 + sj] = __expf(s);
  __syncthreads();

  const size_t yrow = (size_t)bh * ROWS_PER_BH + ro + blk * 16;
  if (tid < 16) {
    float t = 0.f;
#pragma unroll
    for (int j = 0; j < 16; j++) t += As[tid * 17 + j];
    aall[yrow + tid] = t;
  }

  const int yi = tid >> 4, d0 = (tid & 15) * 4;
  float y0 = 0.f, y1 = 0.f, y2 = 0.f, y3 = 0.f;
#pragma unroll
  for (int j = 0; j < 16; j++) {
    float a = As[yi * 17 + j];
    y0 += a * vs[j * 65 + d0 + 0];
    y1 += a * vs[j * 65 + d0 + 1];
    y2 += a * vs[j * 65 + d0 + 2];
    y3 += a * vs[j * 65 + d0 + 3];
  }
  float4 yv = {y0, y1, y2, y3};
  *(float4*)&yall[(yrow + yi) * 64 + d0] = yv;
}

// ---- combine: U = sum_l y_l[i>>l] / (sum_l a_l[i>>l] + eps) ---------------
__global__ __launch_bounds__(256) void combine_kernel(
    const float* __restrict__ yall, const float* __restrict__ aall,
    __hip_bfloat16* __restrict__ Ub) {
  int idx = blockIdx.x * 256 + threadIdx.x;  // 32*4096*64
  int d = idx & 63;
  int i = (idx >> 6) & 4095;
  int bh = idx >> 18;
  size_t base = (size_t)bh * ROWS_PER_BH;
  float Y = 0.f, Aa = 0.f;
#pragma unroll
  for (int l = 0; l < 8; l++) {
    int r = (8192 - (8192 >> l)) + (i >> l);
    Y += yall[(base + r) * 64 + d];
    Aa += aall[base + r];
  }
  float u = Y / (Aa + 1e-8f);
  int b = bh >> 3, h = bh & 7;
  size_t m = (size_t)b * 4096 + i;
  Ub[m * 512 + (size_t)h * 64 + d] = __float2bfloat16(u);
}

// ---------------------------------------------------------------------------
extern "C" void kernel_launch(void* const* d_in, const int* in_sizes, int n_in,
                              void* d_out, int out_size, void* d_ws, size_t ws_size,
                              hipStream_t stream) {
  const float* x     = (const float*)d_in[0];  // [4,4096,1024]
  const float* w_qkv = (const float*)d_in[1];  // [1536,1024]
  const float* w_out = (const float*)d_in[2];  // [1024,512]
  const float* b_out = (const float*)d_in[3];  // [1024]
  float* out = (float*)d_out;

  char* ws = (char*)d_ws;
  __hip_bfloat16* xb    = (__hip_bfloat16*)(ws + 0);           // 33554432 B
  __hip_bfloat16* wqkvb = (__hip_bfloat16*)(ws + 33554432);    //  3145728 B
  __hip_bfloat16* wob   = (__hip_bfloat16*)(ws + 36700160);    //  1048576 B
  __hip_bfloat16* qp    = (__hip_bfloat16*)(ws + 37748736);    // 33423360 B
  __hip_bfloat16* kp    = (__hip_bfloat16*)(ws + 71172096);    // 33423360 B
  __hip_bfloat16* vp    = (__hip_bfloat16*)(ws + 104595456);   // 33423360 B
  float* yall           = (float*)(ws + 138018816);            // 66846720 B
  float* aall           = (float*)(ws + 204865536);            //  1044480 B
  __hip_bfloat16* Ub    = (__hip_bfloat16*)(ws + 205910016);   // 16777216 B
  if (ws_size < 222687232ULL)
    fprintf(stderr, "HAttention1D: ws too small: %zu < 222687232\n", ws_size);

  // 1) converts
  f2b_kernel<<<16384, 256, 0, stream>>>(x, xb, 16777216);
  f2b_kernel<<<1536, 256, 0, stream>>>(w_qkv, wqkvb, 1572864);
  f2b_kernel<<<512, 256, 0, stream>>>(w_out, wob, 524288);

  // 2) qkv projection + scatter
  gemm_qkv_kernel<<<dim3(128, 12), 256, 0, stream>>>(
      (const unsigned short*)xb, (const unsigned short*)wqkvb, qp, kp, vp);

  // 3) pyramid levels 1..7
  const int offs[8] = {0, 4096, 6144, 7168, 7680, 7936, 8064, 8128};
  const int nls[8]  = {4096, 2048, 1024, 512, 256, 128, 64, 32};
  for (int l = 1; l <= 7; ++l) {
    int nOut = nls[l];
    int shift = 0; while ((1 << shift) < nOut) shift++;
    pyramid_kernel<<<nOut * 8, 256, 0, stream>>>(qp, kp, vp, offs[l - 1], offs[l], nOut, shift);
  }

  // 4) block attention over all levels
  attn_kernel<<<dim3(510, 32), 256, 0, stream>>>(qp, kp, vp, yall, aall);

  // 5) combine to U (bf16)
  combine_kernel<<<32768, 256, 0, stream>>>(yall, aall, Ub);

  // 6) out projection + bias
  gemm_out_kernel<<<dim3(128, 8), 256, 0, stream>>>(
      (const unsigned short*)Ub, (const unsigned short*)wob, b_out, out);
}

// Round 2
// 307.499 us; speedup vs baseline: 1.1114x; 1.1114x over previous
//
#include <hip/hip_runtime.h>
#include <hip/hip_bf16.h>
#include <cstdio>

// ---------------------------------------------------------------------------
// HAttention1D: B=4 N=4096 DIM=1024 HEADS=8 DH=64 BSZ=16, 8 levels (0..7)
//  1) f2b: x, w_qkv, w_out -> bf16
//  2) gemm_qkv (bf16 MFMA): qkv = x @ w_qkv^T, scatter epilogue (q*0.125)
//  3) pyramid x7: level l from l-1 (q,k mean; v sum)
//  4) attn: ONE WAVE per 16x16 block, MFMA S^T=k.q^T then PV, no barriers
//  5) combine: U = sum_l y_l / (sum_l a_l + eps) -> bf16
//  6) gemm_out (bf16 MFMA): out = U @ w_out^T + b_out
// ---------------------------------------------------------------------------

typedef __bf16 bf16x8 __attribute__((ext_vector_type(8)));
typedef float floatx4 __attribute__((ext_vector_type(4)));
typedef unsigned short ushortx8 __attribute__((ext_vector_type(8)));
typedef unsigned int uintx4 __attribute__((ext_vector_type(4)));

#define ROWS_PER_BH 8160  // 4096+2048+1024+512+256+128+64+32

__device__ __forceinline__ void g2lds16(const void* g, void* l) {
  __builtin_amdgcn_global_load_lds(
      (const __attribute__((address_space(1))) void*)g,
      (__attribute__((address_space(3))) void*)l, 16, 0, 0);
}

__device__ __forceinline__ unsigned short f2bu(float x) {
  __hip_bfloat16 h = __float2bfloat16(x);
  return *(unsigned short*)&h;
}
__device__ __forceinline__ float bu2f(unsigned short u) {
  __hip_bfloat16 h = *(__hip_bfloat16*)&u;
  return __bfloat162float(h);
}

// ---- fp32 -> bf16 convert, 4 elems/thread ---------------------------------
__global__ __launch_bounds__(256) void f2b_kernel(const float* __restrict__ s,
                                                  __hip_bfloat16* __restrict__ d,
                                                  int n) {
  int i0 = (blockIdx.x * 256 + threadIdx.x) * 4;
  if (i0 + 3 < n) {
    float4 v = *(const float4*)(s + i0);
    d[i0 + 0] = __float2bfloat16(v.x);
    d[i0 + 1] = __float2bfloat16(v.y);
    d[i0 + 2] = __float2bfloat16(v.z);
    d[i0 + 3] = __float2bfloat16(v.w);
  }
}

// ---- GEMM1: qkv = x[16384,1024] @ w_qkv[1536,1024]^T, scatter epilogue ----
__global__ __launch_bounds__(256) void gemm_qkv_kernel(
    const unsigned short* __restrict__ A,   // xb [16384,1024] bf16
    const unsigned short* __restrict__ B,   // wqkvb [1536,1024] bf16
    __hip_bfloat16* __restrict__ qp, __hip_bfloat16* __restrict__ kp,
    __hip_bfloat16* __restrict__ vp) {
  const int K = 1024;
  __shared__ unsigned short ldsA[128 * 32];
  __shared__ unsigned short ldsB[128 * 32];
  const int tid = threadIdx.x;
  const int lane = tid & 63, w = tid >> 6;
  const int wm = w >> 1, wn = w & 1;
  const int tM = blockIdx.x * 128, tN = blockIdx.y * 128;

  const unsigned short* Ag = A + (size_t)(tM + w * 32 + (lane >> 2)) * K + (lane & 3) * 8;
  const unsigned short* Bg = B + (size_t)(tN + w * 32 + (lane >> 2)) * K + (lane & 3) * 8;
  unsigned short* lA = &ldsA[w * 1024 + lane * 8];
  unsigned short* lB = &ldsB[w * 1024 + lane * 8];

  floatx4 acc[4][4];
#pragma unroll
  for (int i = 0; i < 4; i++)
#pragma unroll
    for (int j = 0; j < 4; j++) acc[i][j] = (floatx4){0.f, 0.f, 0.f, 0.f};

  const int rA = wm * 64 + (lane & 15);
  const int rB = wn * 64 + (lane & 15);
  const int kc = (lane >> 4) * 8;

  for (int kt = 0; kt < K; kt += 32) {
    __syncthreads();
    g2lds16(Ag + kt, lA);
    g2lds16(Ag + 16 * K + kt, lA + 512);
    g2lds16(Bg + kt, lB);
    g2lds16(Bg + 16 * K + kt, lB + 512);
    __syncthreads();
    bf16x8 af[4], bv[4];
#pragma unroll
    for (int i = 0; i < 4; i++) af[i] = *(const bf16x8*)&ldsA[(rA + i * 16) * 32 + kc];
#pragma unroll
    for (int j = 0; j < 4; j++) bv[j] = *(const bf16x8*)&ldsB[(rB + j * 16) * 32 + kc];
#pragma unroll
    for (int i = 0; i < 4; i++)
#pragma unroll
      for (int j = 0; j < 4; j++)
        acc[i][j] = __builtin_amdgcn_mfma_f32_16x16x32_bf16(af[i], bv[j], acc[i][j], 0, 0, 0);
  }

  // epilogue: C/D layout col=lane&15, row=(lane>>4)*4+r  [verified m89]
  const int quad = lane >> 4;
#pragma unroll
  for (int i = 0; i < 4; i++) {
#pragma unroll
    for (int j = 0; j < 4; j++) {
      const int c = tN + wn * 64 + j * 16 + (lane & 15);
      const int tensor = c >> 9;         // 0=q 1=k 2=v
      const int rem = c & 511;
      const int h = rem >> 6, d = rem & 63;
      __hip_bfloat16* dstbuf = (tensor == 0) ? qp : ((tensor == 1) ? kp : vp);
      const float scale = (tensor == 0) ? 0.125f : 1.0f;  // DH^-0.5
#pragma unroll
      for (int r = 0; r < 4; r++) {
        const int m = tM + wm * 64 + i * 16 + quad * 4 + r;
        const int b = m >> 12, n = m & 4095;
        size_t dst = ((size_t)(b * 8 + h) * ROWS_PER_BH + n) * 64 + d;
        dstbuf[dst] = __float2bfloat16(acc[i][j][r] * scale);
      }
    }
  }
}

// ---- GEMM2: out = U[16384,512] @ w_out[1024,512]^T + b_out ----------------
__global__ __launch_bounds__(256) void gemm_out_kernel(
    const unsigned short* __restrict__ A,   // Ub [16384,512] bf16
    const unsigned short* __restrict__ B,   // wob [1024,512] bf16
    const float* __restrict__ bias, float* __restrict__ out) {
  const int K = 512;
  __shared__ unsigned short ldsA[128 * 32];
  __shared__ unsigned short ldsB[128 * 32];
  const int tid = threadIdx.x;
  const int lane = tid & 63, w = tid >> 6;
  const int wm = w >> 1, wn = w & 1;
  const int tM = blockIdx.x * 128, tN = blockIdx.y * 128;

  const unsigned short* Ag = A + (size_t)(tM + w * 32 + (lane >> 2)) * K + (lane & 3) * 8;
  const unsigned short* Bg = B + (size_t)(tN + w * 32 + (lane >> 2)) * K + (lane & 3) * 8;
  unsigned short* lA = &ldsA[w * 1024 + lane * 8];
  unsigned short* lB = &ldsB[w * 1024 + lane * 8];

  floatx4 acc[4][4];
#pragma unroll
  for (int i = 0; i < 4; i++)
#pragma unroll
    for (int j = 0; j < 4; j++) acc[i][j] = (floatx4){0.f, 0.f, 0.f, 0.f};

  const int rA = wm * 64 + (lane & 15);
  const int rB = wn * 64 + (lane & 15);
  const int kc = (lane >> 4) * 8;

  for (int kt = 0; kt < K; kt += 32) {
    __syncthreads();
    g2lds16(Ag + kt, lA);
    g2lds16(Ag + 16 * K + kt, lA + 512);
    g2lds16(Bg + kt, lB);
    g2lds16(Bg + 16 * K + kt, lB + 512);
    __syncthreads();
    bf16x8 af[4], bv[4];
#pragma unroll
    for (int i = 0; i < 4; i++) af[i] = *(const bf16x8*)&ldsA[(rA + i * 16) * 32 + kc];
#pragma unroll
    for (int j = 0; j < 4; j++) bv[j] = *(const bf16x8*)&ldsB[(rB + j * 16) * 32 + kc];
#pragma unroll
    for (int i = 0; i < 4; i++)
#pragma unroll
      for (int j = 0; j < 4; j++)
        acc[i][j] = __builtin_amdgcn_mfma_f32_16x16x32_bf16(af[i], bv[j], acc[i][j], 0, 0, 0);
  }

  const int quad = lane >> 4;
#pragma unroll
  for (int i = 0; i < 4; i++) {
#pragma unroll
    for (int j = 0; j < 4; j++) {
      const int c = tN + wn * 64 + j * 16 + (lane & 15);
      const float bb = bias[c];
#pragma unroll
      for (int r = 0; r < 4; r++) {
        const int m = tM + wm * 64 + i * 16 + quad * 4 + r;
        out[(size_t)m * 1024 + c] = acc[i][j][r] + bb;
      }
    }
  }
}

// ---- pyramid: level l from level l-1 (q,k mean; v sum) --------------------
__global__ __launch_bounds__(256) void pyramid_kernel(
    __hip_bfloat16* __restrict__ qp, __hip_bfloat16* __restrict__ kp,
    __hip_bfloat16* __restrict__ vp, int srcRow, int dstRow, int nOut, int shift) {
  int idx = blockIdx.x * 256 + threadIdx.x;
  if (idx >= 32 * nOut * 64) return;
  int d = idx & 63;
  int i = (idx >> 6) & (nOut - 1);
  int bh = idx >> (6 + shift);
  size_t s0 = ((size_t)bh * ROWS_PER_BH + srcRow + 2 * i) * 64 + d;
  size_t dst = ((size_t)bh * ROWS_PER_BH + dstRow + i) * 64 + d;
  float q0 = __bfloat162float(qp[s0]), q1 = __bfloat162float(qp[s0 + 64]);
  float k0 = __bfloat162float(kp[s0]), k1 = __bfloat162float(kp[s0 + 64]);
  float v0 = __bfloat162float(vp[s0]), v1 = __bfloat162float(vp[s0 + 64]);
  qp[dst] = __float2bfloat16(0.5f * (q0 + q1));
  kp[dst] = __float2bfloat16(0.5f * (k0 + k1));
  vp[dst] = __float2bfloat16(v0 + v1);
}

// ---- block attention: ONE WAVE per (level-block, bh), MFMA, no barriers ---
// S^T = k_tile . q_tile^T via mfma (operand swap) so lane holds
// P[i=lane&15][j=quad*4+r] == exactly the rows needed for the PV A-operand.
__global__ __launch_bounds__(256) void attn_kernel(
    const unsigned short* __restrict__ qp, const unsigned short* __restrict__ kp,
    const unsigned short* __restrict__ vp, float* __restrict__ yall,
    float* __restrict__ aall) {
  __shared__ __align__(16) unsigned short vT[4][64 * 24];  // per-wave slice, stride 24
  const int w = threadIdx.x >> 6, lane = threadIdx.x & 63;
  const int g = blockIdx.x * 4 + w;
  if (g >= 510) return;
  const int bh = blockIdx.y;
  int level, blk;
  if (g < 256)      { level = 0; blk = g; }
  else if (g < 384) { level = 1; blk = g - 256; }
  else if (g < 448) { level = 2; blk = g - 384; }
  else if (g < 480) { level = 3; blk = g - 448; }
  else if (g < 496) { level = 4; blk = g - 480; }
  else if (g < 504) { level = 5; blk = g - 496; }
  else if (g < 508) { level = 6; blk = g - 504; }
  else              { level = 7; blk = g - 508; }
  const int ro = 8192 - (8192 >> level);
  const int kblk = (level == 0) ? blk : (blk ^ 1);  // sibling key flip (v NOT flipped)
  const int m = lane & 15, q = lane >> 4;
  const size_t qbase = ((size_t)bh * ROWS_PER_BH + ro + blk * 16) * 64;
  const size_t kbase = ((size_t)bh * ROWS_PER_BH + ro + kblk * 16) * 64;

  // fragment loads: A-op = k rows, B-op = q rows (both contiguous 8 bf16)
  const bf16x8 ka0 = *(const bf16x8*)(kp + kbase + m * 64 + q * 8);
  const bf16x8 ka1 = *(const bf16x8*)(kp + kbase + m * 64 + 32 + q * 8);
  const bf16x8 qb0 = *(const bf16x8*)(qp + qbase + m * 64 + q * 8);
  const bf16x8 qb1 = *(const bf16x8*)(qp + qbase + m * 64 + 32 + q * 8);

  // stage v transposed into LDS: vT[d][vrow], row stride 24 (aligned b128 reads)
  const ushortx8 v0 = *(const ushortx8*)(vp + qbase + m * 64 + q * 16);
  const ushortx8 v1 = *(const ushortx8*)(vp + qbase + m * 64 + q * 16 + 8);
  unsigned short* vtw = vT[w];
#pragma unroll
  for (int j = 0; j < 8; j++) vtw[(q * 16 + j) * 24 + m] = v0[j];
#pragma unroll
  for (int j = 0; j < 8; j++) vtw[(q * 16 + 8 + j) * 24 + m] = v1[j];

  // S^T: D[j=quad*4+r][i=lane&15] = sum_d k[j][d] q[i][d]
  floatx4 s = (floatx4){0.f, 0.f, 0.f, 0.f};
  s = __builtin_amdgcn_mfma_f32_16x16x32_bf16(ka0, qb0, s, 0, 0, 0);
  s = __builtin_amdgcn_mfma_f32_16x16x32_bf16(ka1, qb1, s, 0, 0, 0);

  // P = exp(S), rounded to bf16 (numerator and denominator use SAME values)
  unsigned short pb0 = f2bu(__expf(s[0])), pb1 = f2bu(__expf(s[1]));
  unsigned short pb2 = f2bu(__expf(s[2])), pb3 = f2bu(__expf(s[3]));
  float asum = bu2f(pb0) + bu2f(pb1) + bu2f(pb2) + bu2f(pb3);
  asum += __shfl_xor(asum, 16, 64);
  asum += __shfl_xor(asum, 32, 64);
  const size_t arow = (size_t)bh * ROWS_PER_BH + ro + blk * 16;
  if (q == 0) aall[arow + m] = asum;

  // A-fragment for PV: lane (m,q<2) needs P[m][8q..8q+7] from lanes m+32q, m+32q+16
  unsigned int d0 = (unsigned int)pb0 | ((unsigned int)pb1 << 16);
  unsigned int d1 = (unsigned int)pb2 | ((unsigned int)pb3 << 16);
  const int s0l = m + 32 * (q & 1);
  unsigned int u0 = __shfl(d0, s0l, 64);
  unsigned int u1 = __shfl(d1, s0l, 64);
  unsigned int u2 = __shfl(d0, s0l + 16, 64);
  unsigned int u3 = __shfl(d1, s0l + 16, 64);
  union { uintx4 i; bf16x8 b; } pau;
  pau.i = (q < 2) ? (uintx4){u0, u1, u2, u3} : (uintx4){0u, 0u, 0u, 0u};
  const bf16x8 pa = pau.b;

  // Y = P . v, 4 column chunks of 16; K padded to 32 with zeros
  const bf16x8 bz = pau.b;  // placeholder type
#pragma unroll
  for (int c = 0; c < 4; c++) {
    union { uintx4 i; bf16x8 b; } bvu;
    bvu.i = (uintx4){0u, 0u, 0u, 0u};
    if (q < 2) bvu.b = *(const bf16x8*)&vtw[(c * 16 + m) * 24 + q * 8];
    floatx4 y = (floatx4){0.f, 0.f, 0.f, 0.f};
    y = __builtin_amdgcn_mfma_f32_16x16x32_bf16(pa, bvu.b, y, 0, 0, 0);
#pragma unroll
    for (int r = 0; r < 4; r++)
      yall[(arow + q * 4 + r) * 64 + c * 16 + m] = y[r];
  }
  (void)bz;
}

// ---- combine: U = sum_l y_l[i>>l] / (sum_l a_l[i>>l] + eps) ---------------
__global__ __launch_bounds__(256) void combine_kernel(
    const float* __restrict__ yall, const float* __restrict__ aall,
    __hip_bfloat16* __restrict__ Ub) {
  int idx = blockIdx.x * 256 + threadIdx.x;  // 32*4096*64
  int d = idx & 63;
  int i = (idx >> 6) & 4095;
  int bh = idx >> 18;
  size_t base = (size_t)bh * ROWS_PER_BH;
  float Y = 0.f, Aa = 0.f;
#pragma unroll
  for (int l = 0; l < 8; l++) {
    int r = (8192 - (8192 >> l)) + (i >> l);
    Y += yall[(base + r) * 64 + d];
    Aa += aall[base + r];
  }
  float u = Y / (Aa + 1e-8f);
  int b = bh >> 3, h = bh & 7;
  size_t m = (size_t)b * 4096 + i;
  Ub[m * 512 + (size_t)h * 64 + d] = __float2bfloat16(u);
}

// ---------------------------------------------------------------------------
extern "C" void kernel_launch(void* const* d_in, const int* in_sizes, int n_in,
                              void* d_out, int out_size, void* d_ws, size_t ws_size,
                              hipStream_t stream) {
  const float* x     = (const float*)d_in[0];  // [4,4096,1024]
  const float* w_qkv = (const float*)d_in[1];  // [1536,1024]
  const float* w_out = (const float*)d_in[2];  // [1024,512]
  const float* b_out = (const float*)d_in[3];  // [1024]
  float* out = (float*)d_out;

  char* ws = (char*)d_ws;
  __hip_bfloat16* xb    = (__hip_bfloat16*)(ws + 0);           // 33554432 B
  __hip_bfloat16* wqkvb = (__hip_bfloat16*)(ws + 33554432);    //  3145728 B
  __hip_bfloat16* wob   = (__hip_bfloat16*)(ws + 36700160);    //  1048576 B
  __hip_bfloat16* qp    = (__hip_bfloat16*)(ws + 37748736);    // 33423360 B
  __hip_bfloat16* kp    = (__hip_bfloat16*)(ws + 71172096);    // 33423360 B
  __hip_bfloat16* vp    = (__hip_bfloat16*)(ws + 104595456);   // 33423360 B
  float* yall           = (float*)(ws + 138018816);            // 66846720 B
  float* aall           = (float*)(ws + 204865536);            //  1044480 B
  __hip_bfloat16* Ub    = (__hip_bfloat16*)(ws + 205910016);   // 16777216 B
  if (ws_size < 222687232ULL)
    fprintf(stderr, "HAttention1D: ws too small: %zu < 222687232\n", ws_size);

  // 1) converts
  f2b_kernel<<<16384, 256, 0, stream>>>(x, xb, 16777216);
  f2b_kernel<<<1536, 256, 0, stream>>>(w_qkv, wqkvb, 1572864);
  f2b_kernel<<<512, 256, 0, stream>>>(w_out, wob, 524288);

  // 2) qkv projection + scatter
  gemm_qkv_kernel<<<dim3(128, 12), 256, 0, stream>>>(
      (const unsigned short*)xb, (const unsigned short*)wqkvb, qp, kp, vp);

  // 3) pyramid levels 1..7
  const int offs[8] = {0, 4096, 6144, 7168, 7680, 7936, 8064, 8128};
  const int nls[8]  = {4096, 2048, 1024, 512, 256, 128, 64, 32};
  for (int l = 1; l <= 7; ++l) {
    int nOut = nls[l];
    int shift = 0; while ((1 << shift) < nOut) shift++;
    pyramid_kernel<<<nOut * 8, 256, 0, stream>>>(qp, kp, vp, offs[l - 1], offs[l], nOut, shift);
  }

  // 4) block attention over all levels (1 wave / block, 4 waves / wg)
  attn_kernel<<<dim3(128, 32), 256, 0, stream>>>(
      (const unsigned short*)qp, (const unsigned short*)kp,
      (const unsigned short*)vp, yall, aall);

  // 5) combine to U (bf16)
  combine_kernel<<<32768, 256, 0, stream>>>(yall, aall, Ub);

  // 6) out projection + bias
  gemm_out_kernel<<<dim3(128, 8), 256, 0, stream>>>(
      (const unsigned short*)Ub, (const unsigned short*)wob, b_out, out);
}

// Round 5
// 276.114 us; speedup vs baseline: 1.2377x; 1.1137x over previous
//
#include <hip/hip_runtime.h>
#include <hip/hip_bf16.h>

// ---------------------------------------------------------------------------
// HAttention1D: B=4 N=4096 DIM=1024 HEADS=8 DH=64 BSZ=16, 8 levels (0..7)
//  1) f2b: x, w_qkv, w_out -> bf16
//  2) gemm_qkv (bf16 MFMA, BK=64, XOR-swizzled LDS): qkv = x @ w_qkv^T,
//     scatter epilogue (q*0.125) into (bh,row,d) pyramids
//  3) pyramid_all: ONE kernel, per-(bh,128-row-chunk) WG computes levels 1..7
//     in-place in LDS (strided positions), writes each level to global
//  4) attn: ONE WAVE per 16x16 block, MFMA S^T=k.q^T then PV; y stored bf16
//  5) combine: U = sum_l y_l / (sum_l a_l + eps) -> bf16
//  6) gemm_out (bf16 MFMA, BK=64, swizzled): out = U @ w_out^T + b_out
// ---------------------------------------------------------------------------

typedef __bf16 bf16x8 __attribute__((ext_vector_type(8)));
typedef float floatx4 __attribute__((ext_vector_type(4)));
typedef unsigned short ushortx8 __attribute__((ext_vector_type(8)));
typedef unsigned int uintx4 __attribute__((ext_vector_type(4)));

#define ROWS_PER_BH 8160  // 4096+2048+1024+512+256+128+64+32

__device__ __forceinline__ void g2lds16(const void* g, void* l) {
  __builtin_amdgcn_global_load_lds(
      (const __attribute__((address_space(1))) void*)g,
      (__attribute__((address_space(3))) void*)l, 16, 0, 0);
}

__device__ __forceinline__ unsigned short f2bu(float x) {
  __hip_bfloat16 h = __float2bfloat16(x);
  return *(unsigned short*)&h;
}
__device__ __forceinline__ float bu2f(unsigned short u) {
  __hip_bfloat16 h = *(__hip_bfloat16*)&u;
  return __bfloat162float(h);
}

// ---- fp32 -> bf16 convert, 4 elems/thread ---------------------------------
__global__ __launch_bounds__(256) void f2b_kernel(const float* __restrict__ s,
                                                  __hip_bfloat16* __restrict__ d,
                                                  int n) {
  int i0 = (blockIdx.x * 256 + threadIdx.x) * 4;
  if (i0 + 3 < n) {
    float4 v = *(const float4*)(s + i0);
    d[i0 + 0] = __float2bfloat16(v.x);
    d[i0 + 1] = __float2bfloat16(v.y);
    d[i0 + 2] = __float2bfloat16(v.z);
    d[i0 + 3] = __float2bfloat16(v.w);
  }
}

// ---- shared GEMM core: 128x128 tile, BK=64, XOR-swizzled LDS --------------
// Staging: lane loads global chunk (lane&7)^(lane>>3) of its row, so LDS
// position p of row r holds chunk p^(r&7). Fragment ds_read_b128 at position
// (kk*4+quad)^(lane&7) -> every quad spans all 8 bank groups (2-way = free).
template <int K>
__device__ __forceinline__ void gemm_core(const unsigned short* __restrict__ A,
                                          const unsigned short* __restrict__ B,
                                          unsigned short* ldsA, unsigned short* ldsB,
                                          int tM, int tN, floatx4 acc[4][4]) {
  const int tid = threadIdx.x;
  const int lane = tid & 63, w = tid >> 6;
  const int wm = w >> 1, wn = w & 1;
  const int lr = lane >> 3;            // row-within-8 for staging
  const int gch = (lane & 7) ^ lr;     // XOR-swizzled global chunk
  const unsigned short* Ag = A + (size_t)(tM + w * 32 + lr) * K + gch * 8;
  const unsigned short* Bg = B + (size_t)(tN + w * 32 + lr) * K + gch * 8;
  unsigned short* lA = &ldsA[w * 2048 + lane * 8];
  unsigned short* lB = &ldsB[w * 2048 + lane * 8];

  const int rA = wm * 64 + (lane & 15);
  const int rB = wn * 64 + (lane & 15);
  const int quad = lane >> 4;
  const int sw = lane & 7;             // fragment row & 7

  for (int kt = 0; kt < K; kt += 64) {
    __syncthreads();
#pragma unroll
    for (int c = 0; c < 4; c++) {
      g2lds16(Ag + (size_t)(c * 8) * K + kt, lA + c * 512);
      g2lds16(Bg + (size_t)(c * 8) * K + kt, lB + c * 512);
    }
    __syncthreads();
#pragma unroll
    for (int kk = 0; kk < 2; kk++) {
      bf16x8 af[4], bv[4];
#pragma unroll
      for (int i = 0; i < 4; i++)
        af[i] = *(const bf16x8*)&ldsA[(rA + i * 16) * 64 + (((kk * 4 + quad) ^ sw) * 8)];
#pragma unroll
      for (int j = 0; j < 4; j++)
        bv[j] = *(const bf16x8*)&ldsB[(rB + j * 16) * 64 + (((kk * 4 + quad) ^ sw) * 8)];
#pragma unroll
      for (int i = 0; i < 4; i++)
#pragma unroll
        for (int j = 0; j < 4; j++)
          acc[i][j] = __builtin_amdgcn_mfma_f32_16x16x32_bf16(af[i], bv[j], acc[i][j], 0, 0, 0);
    }
  }
}

// ---- GEMM1: qkv = x[16384,1024] @ w_qkv[1536,1024]^T, scatter epilogue ----
__global__ __launch_bounds__(256) void gemm_qkv_kernel(
    const unsigned short* __restrict__ A,   // xb [16384,1024] bf16
    const unsigned short* __restrict__ B,   // wqkvb [1536,1024] bf16
    __hip_bfloat16* __restrict__ qp, __hip_bfloat16* __restrict__ kp,
    __hip_bfloat16* __restrict__ vp) {
  __shared__ unsigned short ldsA[128 * 64];
  __shared__ unsigned short ldsB[128 * 64];
  const int lane = threadIdx.x & 63, w = threadIdx.x >> 6;
  const int wm = w >> 1, wn = w & 1;
  const int tM = blockIdx.x * 128, tN = blockIdx.y * 128;

  floatx4 acc[4][4];
#pragma unroll
  for (int i = 0; i < 4; i++)
#pragma unroll
    for (int j = 0; j < 4; j++) acc[i][j] = (floatx4){0.f, 0.f, 0.f, 0.f};

  gemm_core<1024>(A, B, ldsA, ldsB, tM, tN, acc);

  // epilogue: C/D layout col=lane&15, row=(lane>>4)*4+r  [verified m89]
  const int quad = lane >> 4;
#pragma unroll
  for (int i = 0; i < 4; i++) {
#pragma unroll
    for (int j = 0; j < 4; j++) {
      const int c = tN + wn * 64 + j * 16 + (lane & 15);
      const int tensor = c >> 9;         // 0=q 1=k 2=v
      const int rem = c & 511;
      const int h = rem >> 6, d = rem & 63;
      __hip_bfloat16* dstbuf = (tensor == 0) ? qp : ((tensor == 1) ? kp : vp);
      const float scale = (tensor == 0) ? 0.125f : 1.0f;  // DH^-0.5
#pragma unroll
      for (int r = 0; r < 4; r++) {
        const int m = tM + wm * 64 + i * 16 + quad * 4 + r;
        const int b = m >> 12, n = m & 4095;
        size_t dst = ((size_t)(b * 8 + h) * ROWS_PER_BH + n) * 64 + d;
        dstbuf[dst] = __float2bfloat16(acc[i][j][r] * scale);
      }
    }
  }
}

// ---- GEMM2: out = U[16384,512] @ w_out[1024,512]^T + b_out ----------------
__global__ __launch_bounds__(256) void gemm_out_kernel(
    const unsigned short* __restrict__ A,   // Ub [16384,512] bf16
    const unsigned short* __restrict__ B,   // wob [1024,512] bf16
    const float* __restrict__ bias, float* __restrict__ out) {
  __shared__ unsigned short ldsA[128 * 64];
  __shared__ unsigned short ldsB[128 * 64];
  const int lane = threadIdx.x & 63, w = threadIdx.x >> 6;
  const int wm = w >> 1, wn = w & 1;
  const int tM = blockIdx.x * 128, tN = blockIdx.y * 128;

  floatx4 acc[4][4];
#pragma unroll
  for (int i = 0; i < 4; i++)
#pragma unroll
    for (int j = 0; j < 4; j++) acc[i][j] = (floatx4){0.f, 0.f, 0.f, 0.f};

  gemm_core<512>(A, B, ldsA, ldsB, tM, tN, acc);

  const int quad = lane >> 4;
#pragma unroll
  for (int i = 0; i < 4; i++) {
#pragma unroll
    for (int j = 0; j < 4; j++) {
      const int c = tN + wn * 64 + j * 16 + (lane & 15);
      const float bb = bias[c];
#pragma unroll
      for (int r = 0; r < 4; r++) {
        const int m = tM + wm * 64 + i * 16 + quad * 4 + r;
        out[(size_t)m * 1024 + c] = acc[i][j][r] + bb;
      }
    }
  }
}

// ---- pyramid, single kernel: WG = (bh, 128-row chunk), levels 1..7 --------
// In-place LDS reduction at strided positions: level-l row i lives at
// position i<<l; out position == first source position, sources disjoint
// from writes within a level, so only an inter-level __syncthreads is needed.
__global__ __launch_bounds__(256) void pyramid_all_kernel(
    __hip_bfloat16* __restrict__ qp, __hip_bfloat16* __restrict__ kp,
    __hip_bfloat16* __restrict__ vp) {
  __shared__ unsigned short qs[128 * 64], ks[128 * 64], vs[128 * 64];  // 48 KB
  const int bh = blockIdx.x >> 5;
  const int chunk = blockIdx.x & 31;
  const int tid = threadIdx.x;
  const size_t base = (size_t)bh * ROWS_PER_BH;
  const size_t g0 = (base + chunk * 128) * 64;
  const unsigned short* qg = (const unsigned short*)qp;
  const unsigned short* kg = (const unsigned short*)kp;
  const unsigned short* vg = (const unsigned short*)vp;
#pragma unroll
  for (int c = 0; c < 4; c++) {
    int off = c * 2048 + tid * 8;
    *(ushortx8*)&qs[off] = *(const ushortx8*)(qg + g0 + off);
    *(ushortx8*)&ks[off] = *(const ushortx8*)(kg + g0 + off);
    *(ushortx8*)&vs[off] = *(const ushortx8*)(vg + g0 + off);
  }
  const int offs[8] = {0, 4096, 6144, 7168, 7680, 7936, 8064, 8128};
#pragma unroll
  for (int l = 1; l <= 7; l++) {
    __syncthreads();
    const int nOut = 128 >> l;
    for (int e = tid; e < nOut * 32; e += 256) {
      const int i = e >> 5, dp = (e & 31) * 2;
      const int a = (i << l) * 64 + dp;
      const int b = a + (1 << (l - 1)) * 64;
      unsigned short q0 = f2bu(0.5f * (bu2f(qs[a]) + bu2f(qs[b])));
      unsigned short q1 = f2bu(0.5f * (bu2f(qs[a + 1]) + bu2f(qs[b + 1])));
      unsigned short k0 = f2bu(0.5f * (bu2f(ks[a]) + bu2f(ks[b])));
      unsigned short k1 = f2bu(0.5f * (bu2f(ks[a + 1]) + bu2f(ks[b + 1])));
      unsigned short v0 = f2bu(bu2f(vs[a]) + bu2f(vs[b]));
      unsigned short v1 = f2bu(bu2f(vs[a + 1]) + bu2f(vs[b + 1]));
      qs[a] = q0; qs[a + 1] = q1;
      ks[a] = k0; ks[a + 1] = k1;
      vs[a] = v0; vs[a + 1] = v1;
      const size_t grow = (base + offs[l] + (size_t)chunk * nOut + i) * 64 + dp;
      *(unsigned int*)((unsigned short*)qp + grow) = (unsigned int)q0 | ((unsigned int)q1 << 16);
      *(unsigned int*)((unsigned short*)kp + grow) = (unsigned int)k0 | ((unsigned int)k1 << 16);
      *(unsigned int*)((unsigned short*)vp + grow) = (unsigned int)v0 | ((unsigned int)v1 << 16);
    }
  }
}

// ---- block attention: ONE WAVE per (level-block, bh), MFMA, no barriers ---
__global__ __launch_bounds__(256) void attn_kernel(
    const unsigned short* __restrict__ qp, const unsigned short* __restrict__ kp,
    const unsigned short* __restrict__ vp, __hip_bfloat16* __restrict__ yall,
    float* __restrict__ aall) {
  __shared__ __align__(16) unsigned short vT[4][64 * 24];  // per-wave slice, stride 24
  const int w = threadIdx.x >> 6, lane = threadIdx.x & 63;
  const int g = blockIdx.x * 4 + w;
  if (g >= 510) return;
  const int bh = blockIdx.y;
  int level, blk;
  if (g < 256)      { level = 0; blk = g; }
  else if (g < 384) { level = 1; blk = g - 256; }
  else if (g < 448) { level = 2; blk = g - 384; }
  else if (g < 480) { level = 3; blk = g - 448; }
  else if (g < 496) { level = 4; blk = g - 480; }
  else if (g < 504) { level = 5; blk = g - 496; }
  else if (g < 508) { level = 6; blk = g - 504; }
  else              { level = 7; blk = g - 508; }
  const int ro = 8192 - (8192 >> level);
  const int kblk = (level == 0) ? blk : (blk ^ 1);  // sibling key flip (v NOT flipped)
  const int m = lane & 15, q = lane >> 4;
  const size_t qbase = ((size_t)bh * ROWS_PER_BH + ro + blk * 16) * 64;
  const size_t kbase = ((size_t)bh * ROWS_PER_BH + ro + kblk * 16) * 64;

  // fragment loads: A-op = k rows, B-op = q rows (both contiguous 8 bf16)
  const bf16x8 ka0 = *(const bf16x8*)(kp + kbase + m * 64 + q * 8);
  const bf16x8 ka1 = *(const bf16x8*)(kp + kbase + m * 64 + 32 + q * 8);
  const bf16x8 qb0 = *(const bf16x8*)(qp + qbase + m * 64 + q * 8);
  const bf16x8 qb1 = *(const bf16x8*)(qp + qbase + m * 64 + 32 + q * 8);

  // stage v transposed into LDS: vT[d][vrow], row stride 24
  const ushortx8 v0 = *(const ushortx8*)(vp + qbase + m * 64 + q * 16);
  const ushortx8 v1 = *(const ushortx8*)(vp + qbase + m * 64 + q * 16 + 8);
  unsigned short* vtw = vT[w];
#pragma unroll
  for (int j = 0; j < 8; j++) vtw[(q * 16 + j) * 24 + m] = v0[j];
#pragma unroll
  for (int j = 0; j < 8; j++) vtw[(q * 16 + 8 + j) * 24 + m] = v1[j];

  // S^T: D[j=quad*4+r][i=lane&15] = sum_d k[j][d] q[i][d]
  floatx4 s = (floatx4){0.f, 0.f, 0.f, 0.f};
  s = __builtin_amdgcn_mfma_f32_16x16x32_bf16(ka0, qb0, s, 0, 0, 0);
  s = __builtin_amdgcn_mfma_f32_16x16x32_bf16(ka1, qb1, s, 0, 0, 0);

  // P = exp(S) in bf16 (numerator & denominator use the SAME rounded values)
  unsigned short pb0 = f2bu(__expf(s[0])), pb1 = f2bu(__expf(s[1]));
  unsigned short pb2 = f2bu(__expf(s[2])), pb3 = f2bu(__expf(s[3]));
  float asum = bu2f(pb0) + bu2f(pb1) + bu2f(pb2) + bu2f(pb3);
  asum += __shfl_xor(asum, 16, 64);
  asum += __shfl_xor(asum, 32, 64);
  const size_t arow = (size_t)bh * ROWS_PER_BH + ro + blk * 16;
  if (q == 0) aall[arow + m] = asum;

  // A-fragment for PV: lane (m,q<2) needs P[m][8q..8q+7] from lanes m+32q, m+32q+16
  unsigned int d0 = (unsigned int)pb0 | ((unsigned int)pb1 << 16);
  unsigned int d1 = (unsigned int)pb2 | ((unsigned int)pb3 << 16);
  const int s0l = m + 32 * (q & 1);
  unsigned int u0 = __shfl(d0, s0l, 64);
  unsigned int u1 = __shfl(d1, s0l, 64);
  unsigned int u2 = __shfl(d0, s0l + 16, 64);
  unsigned int u3 = __shfl(d1, s0l + 16, 64);
  union { uintx4 i; bf16x8 b; } pau;
  pau.i = (q < 2) ? (uintx4){u0, u1, u2, u3} : (uintx4){0u, 0u, 0u, 0u};
  const bf16x8 pa = pau.b;

  // Y = P . v, 4 column chunks of 16; K padded to 32 with zeros
#pragma unroll
  for (int c = 0; c < 4; c++) {
    union { uintx4 i; bf16x8 b; } bvu;
    bvu.i = (uintx4){0u, 0u, 0u, 0u};
    if (q < 2) bvu.b = *(const bf16x8*)&vtw[(c * 16 + m) * 24 + q * 8];
    floatx4 y = (floatx4){0.f, 0.f, 0.f, 0.f};
    y = __builtin_amdgcn_mfma_f32_16x16x32_bf16(pa, bvu.b, y, 0, 0, 0);
#pragma unroll
    for (int r = 0; r < 4; r++)
      yall[(arow + q * 4 + r) * 64 + c * 16 + m] = __float2bfloat16(y[r]);
  }
}

// ---- combine: U = sum_l y_l[i>>l] / (sum_l a_l[i>>l] + eps) ---------------
__global__ __launch_bounds__(256) void combine_kernel(
    const unsigned short* __restrict__ yall, const float* __restrict__ aall,
    __hip_bfloat16* __restrict__ Ub) {
  int idx = blockIdx.x * 256 + threadIdx.x;  // 32*4096*64
  int d = idx & 63;
  int i = (idx >> 6) & 4095;
  int bh = idx >> 18;
  size_t base = (size_t)bh * ROWS_PER_BH;
  float Y = 0.f, Aa = 0.f;
#pragma unroll
  for (int l = 0; l < 8; l++) {
    int r = (8192 - (8192 >> l)) + (i >> l);
    Y += bu2f(yall[(base + r) * 64 + d]);
    Aa += aall[base + r];
  }
  float u = Y / (Aa + 1e-8f);
  int b = bh >> 3, h = bh & 7;
  size_t m = (size_t)b * 4096 + i;
  Ub[m * 512 + (size_t)h * 64 + d] = __float2bfloat16(u);
}

// ---------------------------------------------------------------------------
extern "C" void kernel_launch(void* const* d_in, const int* in_sizes, int n_in,
                              void* d_out, int out_size, void* d_ws, size_t ws_size,
                              hipStream_t stream) {
  const float* x     = (const float*)d_in[0];  // [4,4096,1024]
  const float* w_qkv = (const float*)d_in[1];  // [1536,1024]
  const float* w_out = (const float*)d_in[2];  // [1024,512]
  const float* b_out = (const float*)d_in[3];  // [1024]
  float* out = (float*)d_out;

  char* ws = (char*)d_ws;
  __hip_bfloat16* xb    = (__hip_bfloat16*)(ws + 0);           // 33554432 B
  __hip_bfloat16* wqkvb = (__hip_bfloat16*)(ws + 33554432);    //  3145728 B
  __hip_bfloat16* wob   = (__hip_bfloat16*)(ws + 36700160);    //  1048576 B
  __hip_bfloat16* qp    = (__hip_bfloat16*)(ws + 37748736);    // 33423360 B
  __hip_bfloat16* kp    = (__hip_bfloat16*)(ws + 71172096);    // 33423360 B
  __hip_bfloat16* vp    = (__hip_bfloat16*)(ws + 104595456);   // 33423360 B
  __hip_bfloat16* yall  = (__hip_bfloat16*)(ws + 138018816);   // 33423360 B
  float* aall           = (float*)(ws + 171442176);            //  1044480 B
  __hip_bfloat16* Ub    = (__hip_bfloat16*)(ws + 172486656);   // 16777216 B

  // 1) converts
  f2b_kernel<<<16384, 256, 0, stream>>>(x, xb, 16777216);
  f2b_kernel<<<1536, 256, 0, stream>>>(w_qkv, wqkvb, 1572864);
  f2b_kernel<<<512, 256, 0, stream>>>(w_out, wob, 524288);

  // 2) qkv projection + scatter
  gemm_qkv_kernel<<<dim3(128, 12), 256, 0, stream>>>(
      (const unsigned short*)xb, (const unsigned short*)wqkvb, qp, kp, vp);

  // 3) pyramid levels 1..7, single launch
  pyramid_all_kernel<<<1024, 256, 0, stream>>>(qp, kp, vp);

  // 4) block attention over all levels (1 wave / block, 4 waves / wg)
  attn_kernel<<<dim3(128, 32), 256, 0, stream>>>(
      (const unsigned short*)qp, (const unsigned short*)kp,
      (const unsigned short*)vp, yall, aall);

  // 5) combine to U (bf16)
  combine_kernel<<<32768, 256, 0, stream>>>((const unsigned short*)yall, aall, Ub);

  // 6) out projection + bias
  gemm_out_kernel<<<dim3(128, 8), 256, 0, stream>>>(
      (const unsigned short*)Ub, (const unsigned short*)wob, b_out, out);
}